// Round 3
// baseline (52.159 us; speedup 1.0000x reference)
//
#include <hip/hip_runtime.h>

// Problem constants (from reference)
#define B 8
#define C 64
#define H 64
#define W 64
#define K 5
#define PAD 2
#define HW (H * W)          // 4096
#define CHW (C * HW)        // 262144
#define TOT (B * CHW)       // 2097152

// Padded k/v plane geometry
#define PH (H + 2 * PAD)    // 68
#define PW (W + 2 * PAD)    // 68
#define PHW (PH * PW)       // 4624
#define PTOT (B * C * PHW)  // 2367488 elements per buffer

#define OCHUNK 16           // output channels per thread in pass 1

// ---------------------------------------------------------------------------
// Pass 0: zero the padded k/v buffers (2 * 9.47 MB). Runs every call so the
// pad ring is deterministically 0 on each graph replay (harness poisons ws
// with 0xAA once and never re-poisons). float4 stores, ~3 us.
// ---------------------------------------------------------------------------
__global__ __launch_bounds__(256) void zero_kernel(float4* __restrict__ p, int n4)
{
    const int i = blockIdx.x * 256 + threadIdx.x;
    if (i < n4) p[i] = make_float4(0.f, 0.f, 0.f, 0.f);
}

// ---------------------------------------------------------------------------
// Pass 1: 1x1 conv (channel contraction) for q, k, v.
// grid = (B*HW/256, 12); blockIdx.y = matrix*4 + ochunk.
// Each thread: one pixel, 16 output channels. x[b,:,h,w] cached in 64 VGPRs
// (coalesced across threads: w is thread-fastest). W reads are wave-uniform
// -> scalar loads. q written to [B,C,64,64]; k,v written into the INTERIOR
// of padded [B,C,68,68] planes (pad ring stays 0 = reference's zero-pad conv).
// ---------------------------------------------------------------------------
__global__ __launch_bounds__(256) void qkv_kernel(
    const float* __restrict__ x,
    const float* __restrict__ Wq,
    const float* __restrict__ Wk,
    const float* __restrict__ Wv,
    float* __restrict__ qb,
    float* __restrict__ kb,
    float* __restrict__ vb)
{
    const int p  = blockIdx.x * blockDim.x + threadIdx.x;  // pixel in [0, B*HW)
    const int b  = p >> 12;                                // / 4096
    const int hw = p & 4095;
    const int h  = hw >> 6;
    const int w  = hw & 63;

    const int y  = blockIdx.y;       // 0..11
    const int m  = y >> 2;           // 0=q, 1=k, 2=v
    const int oc = (y & 3) * OCHUNK; // output channel base

    const float* Wm = (m == 0) ? Wq : (m == 1) ? Wk : Wv;
    Wm += oc * C;

    const float* xp = x + b * CHW + hw;
    float xr[C];
#pragma unroll
    for (int c = 0; c < C; ++c) xr[c] = xp[c * HW];

    float acc[OCHUNK];
#pragma unroll
    for (int o = 0; o < OCHUNK; ++o) acc[o] = 0.f;

#pragma unroll
    for (int c = 0; c < C; ++c) {
        const float xv = xr[c];
#pragma unroll
        for (int o = 0; o < OCHUNK; ++o)
            acc[o] = fmaf(Wm[o * C + c], xv, acc[o]);
    }

    if (m == 0) {
        float* op = qb + b * CHW + oc * HW + hw;
#pragma unroll
        for (int o = 0; o < OCHUNK; ++o) op[o * HW] = acc[o];
    } else {
        float* ob = (m == 1) ? kb : vb;
        float* op = ob + (b * C + oc) * PHW + (h + PAD) * PW + (w + PAD);
#pragma unroll
        for (int o = 0; o < OCHUNK; ++o) op[o * PHW] = acc[o];
    }
}

// ---------------------------------------------------------------------------
// Pass 2: per-channel 5x5 windowed softmax attention, single fused loop.
// Thread per (b,c,h,w). kk = i*K + j (kh-major, matches reference _unfold).
// bias[c][i*K+j] = (c < C/2) ? rel_h[c][i] : rel_w[c - C/2][j].
// k/v planes are padded (pad ring = 0) -> ALL 25 taps are unconditional
// loads: no exec-mask churn, loads pipeline on vmcnt.
// No max-subtraction: |q*(k+bias)| <~ 25 here, exp stays in fp32 range.
// c is constant within a block -> is_h is wave-uniform (no divergence).
// ---------------------------------------------------------------------------
__global__ __launch_bounds__(256) void attn_kernel(
    const float* __restrict__ qb,
    const float* __restrict__ kb,
    const float* __restrict__ vb,
    const float* __restrict__ rel_h,
    const float* __restrict__ rel_w,
    float* __restrict__ out)
{
    const int idx = blockIdx.x * blockDim.x + threadIdx.x;  // [0, TOT)
    const int w = idx & 63;
    const int h = (idx >> 6) & 63;
    const int c = (idx >> 12) & 63;

    const float q = qb[idx];

    const bool is_h = (c < (C / 2));
    const float* rp = is_h ? (rel_h + c * K) : (rel_w + (c - C / 2) * K);
    float qr[K];
#pragma unroll
    for (int t = 0; t < K; ++t) qr[t] = q * rp[t];   // q * bias, hoisted

    const int plane = (idx >> 12) * PHW;  // (b*C + c) * PHW
    const float* kp = kb + plane;
    const float* vp = vb + plane;

    float den = 0.f, num = 0.f;
#pragma unroll
    for (int i = 0; i < K; ++i) {
        // padded row index: hh + PAD = h + i ; padded col: w + j
        const int row = (h + i) * PW + w;
        const float qri = qr[i];
#pragma unroll
        for (int j = 0; j < K; ++j) {
            const float kt = kp[row + j];
            const float vt = vp[row + j];
            const float l = fmaf(q, kt, is_h ? qri : qr[j]);
            const float e = __expf(l);
            den += e;
            num = fmaf(e, vt, num);
        }
    }

    out[idx] = num * __builtin_amdgcn_rcpf(den);
}

// ---------------------------------------------------------------------------
extern "C" void kernel_launch(void* const* d_in, const int* in_sizes, int n_in,
                              void* d_out, int out_size, void* d_ws, size_t ws_size,
                              hipStream_t stream)
{
    const float* x     = (const float*)d_in[0];
    const float* Wq    = (const float*)d_in[1];
    const float* Wk    = (const float*)d_in[2];
    const float* Wv    = (const float*)d_in[3];
    const float* rel_h = (const float*)d_in[4];
    const float* rel_w = (const float*)d_in[5];

    float* qb = (float*)d_ws;        // [B,C,64,64]   8 MB
    float* kb = qb + TOT;            // [B,C,68,68]   9.47 MB (padded)
    float* vb = kb + PTOT;           // [B,C,68,68]   9.47 MB (padded)

    // zero padded k/v buffers (2*PTOT floats, PTOT divisible by 4)
    const int n4 = (2 * PTOT) / 4;
    zero_kernel<<<(n4 + 255) / 256, 256, 0, stream>>>((float4*)kb, n4);

    dim3 g1(B * HW / 256, 12);
    qkv_kernel<<<g1, 256, 0, stream>>>(x, Wq, Wk, Wv, qb, kb, vb);

    attn_kernel<<<TOT / 256, 256, 0, stream>>>(qb, kb, vb, rel_h, rel_w,
                                               (float*)d_out);
}

// Round 4
// 48.070 us; speedup vs baseline: 1.0851x; 1.0851x over previous
//
#include <hip/hip_runtime.h>

// Problem constants (from reference)
#define B 8
#define C 64
#define H 64
#define W 64
#define K 5
#define PAD 2
#define HW (H * W)          // 4096
#define CHW (C * HW)        // 262144
#define TOT (B * CHW)       // 2097152

// Padded k/v plane geometry: 68 valid cols, stride 72 (16B-aligned rows)
#define PH2 68
#define PW2 72
#define PHW2 (PH2 * PW2)    // 4896
#define NPL (B * C)         // 512 planes per buffer

#define OCHUNK 32           // output channels per thread in pass 1

// ---------------------------------------------------------------------------
// Pass 0: zero ONLY the pad ring of the k/v planes (interior is fully
// rewritten by qkv every call -> deterministic). Ring per plane: rows
// {0,1,66,67} full stride-rows (as float4), cols {0,1} and {66,67} of rows
// 2..65 (as float2). 1024 blocks x 256 threads, ~0.5 MB of stores.
// ---------------------------------------------------------------------------
__global__ __launch_bounds__(256) void ring_zero(float* __restrict__ kb,
                                                 float* __restrict__ vb)
{
    const int plane = blockIdx.x;  // 0..2*NPL-1
    float* base = (plane < NPL) ? (kb + plane * PHW2)
                                : (vb + (plane - NPL) * PHW2);
    const int t = threadIdx.x;
    if (t < 72) {                       // 4 edge rows x 18 float4 = 72
        const int r4  = t / 18;         // 0..3
        const int row = (r4 < 2) ? r4 : (64 + r4);  // 0,1,66,67
        ((float4*)(base + row * PW2))[t - r4 * 18] =
            make_float4(0.f, 0.f, 0.f, 0.f);
    } else if (t >= 128) {              // 64 middle rows x 2 sides
        const int m    = t - 128;       // 0..127
        const int row  = 2 + (m >> 1);  // 2..65
        const int side = (m & 1) ? 66 : 0;
        *(float2*)(base + row * PW2 + side) = make_float2(0.f, 0.f);
    }
}

// ---------------------------------------------------------------------------
// Pass 1: 1x1 conv (channel contraction) for q, k, v.
// grid = (B*HW/256, 6); blockIdx.y = matrix*2 + ochunk (32 out-channels per
// thread). x[b,:,h,w] cached in 64 VGPRs (coalesced: w thread-fastest).
// W reads wave-uniform -> scalar loads. q -> [B,C,64,64]; k,v -> interior of
// padded stride-72 planes (ring stays 0 = reference zero-pad conv).
// ---------------------------------------------------------------------------
__global__ __launch_bounds__(256) void qkv_kernel(
    const float* __restrict__ x,
    const float* __restrict__ Wq,
    const float* __restrict__ Wk,
    const float* __restrict__ Wv,
    float* __restrict__ qb,
    float* __restrict__ kb,
    float* __restrict__ vb)
{
    const int p  = blockIdx.x * blockDim.x + threadIdx.x;  // pixel in [0, B*HW)
    const int b  = p >> 12;
    const int hw = p & 4095;
    const int h  = hw >> 6;
    const int w  = hw & 63;

    const int y  = blockIdx.y;       // 0..5
    const int m  = y >> 1;           // 0=q, 1=k, 2=v
    const int oc = (y & 1) * OCHUNK; // output channel base

    const float* Wm = (m == 0) ? Wq : (m == 1) ? Wk : Wv;
    Wm += oc * C;

    const float* xp = x + b * CHW + hw;
    float xr[C];
#pragma unroll
    for (int c = 0; c < C; ++c) xr[c] = xp[c * HW];

    float acc[OCHUNK];
#pragma unroll
    for (int o = 0; o < OCHUNK; ++o) acc[o] = 0.f;

#pragma unroll
    for (int c = 0; c < C; ++c) {
        const float xv = xr[c];
#pragma unroll
        for (int o = 0; o < OCHUNK; ++o)
            acc[o] = fmaf(Wm[o * C + c], xv, acc[o]);
    }

    if (m == 0) {
        float* op = qb + b * CHW + oc * HW + hw;
#pragma unroll
        for (int o = 0; o < OCHUNK; ++o) op[o * HW] = acc[o];
    } else {
        float* ob = (m == 1) ? kb : vb;
        float* op = ob + (b * C + oc) * PHW2 + (h + PAD) * PW2 + (w + PAD);
#pragma unroll
        for (int o = 0; o < OCHUNK; ++o) op[o * PHW2] = acc[o];
    }
}

// ---------------------------------------------------------------------------
// Pass 2: per-channel 5x5 windowed softmax attention, 4 pixels per thread.
// Thread quad p: w0=(p&15)*4, h=(p>>4)&63, plane=p>>10. Taps for pixels
// w0..w0+3 span padded cols [w0, w0+8) = exactly 2 float4 loads per row
// (rows 16B-aligned via stride 72). kk = i*K+j (kh-major = _unfold order);
// bias = (c<32) ? rel_h[c][i] : rel_w[c-32][j]. is_h is block-uniform ->
// the i/j bias branch is non-divergent. No max-subtraction (|logit|<~25,
// fp32-safe; softmax shift-invariant).
// ---------------------------------------------------------------------------
__global__ __launch_bounds__(256) void attn_kernel(
    const float* __restrict__ qb,
    const float* __restrict__ kb,
    const float* __restrict__ vb,
    const float* __restrict__ rel_h,
    const float* __restrict__ rel_w,
    float* __restrict__ out)
{
    const int p  = blockIdx.x * 256 + threadIdx.x;  // quad id [0, TOT/4)
    const int w0 = (p & 15) << 2;
    const int h  = (p >> 4) & 63;
    const int pl = p >> 10;          // b*C + c
    const int c  = pl & 63;

    const float4 qv = *(const float4*)(qb + pl * HW + h * W + w0);
    const float qx[4] = {qv.x, qv.y, qv.z, qv.w};

    const bool is_h = (c < (C / 2));
    const float* rp = is_h ? (rel_h + c * K) : (rel_w + (c - C / 2) * K);
    float r[K];
#pragma unroll
    for (int t = 0; t < K; ++t) r[t] = rp[t];

    const float* kp = kb + pl * PHW2;
    const float* vp = vb + pl * PHW2;

    float den[4] = {0.f, 0.f, 0.f, 0.f};
    float num[4] = {0.f, 0.f, 0.f, 0.f};

    if (is_h) {
#pragma unroll
        for (int i = 0; i < K; ++i) {
            const int off = (h + i) * PW2 + w0;
            const float4 ka = *(const float4*)(kp + off);
            const float4 kc = *(const float4*)(kp + off + 4);
            const float4 va = *(const float4*)(vp + off);
            const float4 vc = *(const float4*)(vp + off + 4);
            const float kr[8] = {ka.x, ka.y, ka.z, ka.w, kc.x, kc.y, kc.z, kc.w};
            const float vr[8] = {va.x, va.y, va.z, va.w, vc.x, vc.y, vc.z, vc.w};
            float qri[4];
#pragma unroll
            for (int px = 0; px < 4; ++px) qri[px] = qx[px] * r[i];
#pragma unroll
            for (int j = 0; j < K; ++j) {
#pragma unroll
                for (int px = 0; px < 4; ++px) {
                    const float e = __expf(fmaf(qx[px], kr[px + j], qri[px]));
                    den[px] += e;
                    num[px] = fmaf(e, vr[px + j], num[px]);
                }
            }
        }
    } else {
        float qrj[4][K];
#pragma unroll
        for (int px = 0; px < 4; ++px)
#pragma unroll
            for (int j = 0; j < K; ++j) qrj[px][j] = qx[px] * r[j];
#pragma unroll
        for (int i = 0; i < K; ++i) {
            const int off = (h + i) * PW2 + w0;
            const float4 ka = *(const float4*)(kp + off);
            const float4 kc = *(const float4*)(kp + off + 4);
            const float4 va = *(const float4*)(vp + off);
            const float4 vc = *(const float4*)(vp + off + 4);
            const float kr[8] = {ka.x, ka.y, ka.z, ka.w, kc.x, kc.y, kc.z, kc.w};
            const float vr[8] = {va.x, va.y, va.z, va.w, vc.x, vc.y, vc.z, vc.w};
#pragma unroll
            for (int j = 0; j < K; ++j) {
#pragma unroll
                for (int px = 0; px < 4; ++px) {
                    const float e = __expf(fmaf(qx[px], kr[px + j], qrj[px][j]));
                    den[px] += e;
                    num[px] = fmaf(e, vr[px + j], num[px]);
                }
            }
        }
    }

    float4 o;
    o.x = num[0] * __builtin_amdgcn_rcpf(den[0]);
    o.y = num[1] * __builtin_amdgcn_rcpf(den[1]);
    o.z = num[2] * __builtin_amdgcn_rcpf(den[2]);
    o.w = num[3] * __builtin_amdgcn_rcpf(den[3]);
    *(float4*)(out + pl * HW + h * W + w0) = o;
}

// ---------------------------------------------------------------------------
extern "C" void kernel_launch(void* const* d_in, const int* in_sizes, int n_in,
                              void* d_out, int out_size, void* d_ws, size_t ws_size,
                              hipStream_t stream)
{
    const float* x     = (const float*)d_in[0];
    const float* Wq    = (const float*)d_in[1];
    const float* Wk    = (const float*)d_in[2];
    const float* Wv    = (const float*)d_in[3];
    const float* rel_h = (const float*)d_in[4];
    const float* rel_w = (const float*)d_in[5];

    float* qb = (float*)d_ws;            // [B,C,64,64]          8 MB
    float* kb = qb + TOT;                // [B,C,68 rows x72]    10 MB (padded)
    float* vb = kb + (size_t)NPL * PHW2; // [B,C,68 rows x72]    10 MB (padded)

    ring_zero<<<2 * NPL, 256, 0, stream>>>(kb, vb);

    dim3 g1(B * HW / 256, 6);
    qkv_kernel<<<g1, 256, 0, stream>>>(x, Wq, Wk, Wv, qb, kb, vb);

    attn_kernel<<<TOT / 4 / 256, 256, 0, stream>>>(qb, kb, vb, rel_h, rel_w,
                                                   (float*)d_out);
}

// Round 5
// 45.050 us; speedup vs baseline: 1.1578x; 1.0670x over previous
//
#include <hip/hip_runtime.h>

// Problem constants (from reference)
#define B 8
#define C 64
#define H 64
#define W 64
#define K 5
#define PAD 2
#define HW (H * W)          // 4096
#define CHW (C * HW)        // 262144
#define TOT (B * CHW)       // 2097152

#define OCHUNK 16           // output channels per thread in pass 1

// attn tiling: block = 16 rows x 64 cols of one (b,c) plane
#define TROWS 16
#define SROWS (TROWS + 2 * PAD)   // 20 staged rows
#define SCOLS 72                  // 64 + 2*PAD, padded to 72 for 16B row alignment
#define NSLOT2 (SROWS * (SCOLS / 2))  // 720 float2 slots per plane

// ---------------------------------------------------------------------------
// Pass 1: 1x1 conv (channel contraction) for q, k, v — identical to round-2
// kernel (known-good measurement baseline). grid = (B*HW/256, 12);
// blockIdx.y = matrix*4 + ochunk. x[b,:,h,w] cached in 64 VGPRs (coalesced:
// w thread-fastest); W reads wave-uniform -> scalar loads. All outputs
// unpadded [B,C,64,64]; pad semantics handled in attn's LDS stage.
// ---------------------------------------------------------------------------
__global__ __launch_bounds__(256) void qkv_kernel(
    const float* __restrict__ x,
    const float* __restrict__ Wq,
    const float* __restrict__ Wk,
    const float* __restrict__ Wv,
    float* __restrict__ qb,
    float* __restrict__ kb,
    float* __restrict__ vb)
{
    const int p  = blockIdx.x * blockDim.x + threadIdx.x;  // pixel in [0, B*HW)
    const int b  = p >> 12;
    const int hw = p & 4095;

    const int y  = blockIdx.y;       // 0..11
    const int m  = y >> 2;           // 0=q, 1=k, 2=v
    const int oc = (y & 3) * OCHUNK; // output channel base

    const float* Wm = (m == 0) ? Wq : (m == 1) ? Wk : Wv;
    float*       ob = (m == 0) ? qb : (m == 1) ? kb : vb;
    Wm += oc * C;

    const float* xp = x + b * CHW + hw;
    float xr[C];
#pragma unroll
    for (int c = 0; c < C; ++c) xr[c] = xp[c * HW];

    float acc[OCHUNK];
#pragma unroll
    for (int o = 0; o < OCHUNK; ++o) acc[o] = 0.f;

#pragma unroll
    for (int c = 0; c < C; ++c) {
        const float xv = xr[c];
#pragma unroll
        for (int o = 0; o < OCHUNK; ++o)
            acc[o] = fmaf(Wm[o * C + c], xv, acc[o]);
    }

    float* op = ob + b * CHW + oc * HW + hw;
#pragma unroll
    for (int o = 0; o < OCHUNK; ++o) op[o * HW] = acc[o];
}

// ---------------------------------------------------------------------------
// Pass 2: per-channel 5x5 windowed softmax attention, LDS-staged.
// Block = quarter-plane: plane pl = bid>>2, rows [h0, h0+16), h0=(bid&3)*16.
// Stage k,v rows h0-2 .. h0+17 into padded 20x72 LDS images (zero ring =
// reference zero-pad; each global k/v element read exactly once, coalesced
// float2). Then each thread computes 4 pixels; all 25 taps are aligned
// float4 LDS reads (row stride 288 B, w0 multiple of 4 -> 16B aligned).
// kk = i*K+j (kh-major = _unfold order); bias = (c<32)?rel_h[c][i]
// :rel_w[c-32][j]; is_h block-uniform. No max-subtraction (|logit|<~25,
// fp32-safe; softmax shift-invariant).
// ---------------------------------------------------------------------------
__global__ __launch_bounds__(256) void attn_kernel(
    const float* __restrict__ qb,
    const float* __restrict__ kb,
    const float* __restrict__ vb,
    const float* __restrict__ rel_h,
    const float* __restrict__ rel_w,
    float* __restrict__ out)
{
    __shared__ __align__(16) float sk[SROWS][SCOLS];
    __shared__ __align__(16) float sv[SROWS][SCOLS];

    const int bid = blockIdx.x;
    const int pl  = bid >> 2;          // b*C + c
    const int h0  = (bid & 3) * TROWS;
    const int c   = pl & 63;
    const int t   = threadIdx.x;

    const float* kp = kb + pl * HW;
    const float* vp = vb + pl * HW;

    // ---- stage: 2 planes * 720 float2 slots ----
    for (int idx = t; idx < 2 * NSLOT2; idx += 256) {
        const int p   = (idx >= NSLOT2);
        const int rem = p ? idx - NSLOT2 : idx;
        const int row = rem / (SCOLS / 2);
        const int c2  = rem - row * (SCOLS / 2);   // float2 col 0..35
        const int g   = h0 + row - PAD;            // global row
        float2 val = make_float2(0.f, 0.f);
        // LDS cols [2,66) hold global cols [0,64): f2 slot c2 covers cols
        // 2*c2, 2*c2+1 -> global w = 2*c2-2 (valid for c2 in [1,32])
        if (((unsigned)g < (unsigned)H) & (c2 >= 1) & (c2 <= 32)) {
            const float* src = (p ? vp : kp) + g * W + (c2 * 2 - 2);
            val = *(const float2*)src;
        }
        float* dst = (p ? &sv[0][0] : &sk[0][0]) + row * SCOLS + c2 * 2;
        *(float2*)dst = val;
    }
    __syncthreads();

    // ---- compute: 1 quad (4 px) per thread ----
    const int lr = t >> 4;             // local row 0..15
    const int w0 = (t & 15) << 2;      // col base 0,4,..,60
    const int h  = h0 + lr;

    const float4 qv = *(const float4*)(qb + pl * HW + h * W + w0);
    const float qx[4] = {qv.x, qv.y, qv.z, qv.w};

    const bool is_h = (c < (C / 2));
    const float* rp = is_h ? (rel_h + c * K) : (rel_w + (c - C / 2) * K);
    float r[K];
#pragma unroll
    for (int u = 0; u < K; ++u) r[u] = rp[u];

    float den[4] = {0.f, 0.f, 0.f, 0.f};
    float num[4] = {0.f, 0.f, 0.f, 0.f};

    if (is_h) {
#pragma unroll
        for (int i = 0; i < K; ++i) {
            const float4 ka = *(const float4*)&sk[lr + i][w0];
            const float4 kc = *(const float4*)&sk[lr + i][w0 + 4];
            const float4 va = *(const float4*)&sv[lr + i][w0];
            const float4 vc = *(const float4*)&sv[lr + i][w0 + 4];
            const float kr[8] = {ka.x, ka.y, ka.z, ka.w, kc.x, kc.y, kc.z, kc.w};
            const float vr[8] = {va.x, va.y, va.z, va.w, vc.x, vc.y, vc.z, vc.w};
            float qri[4];
#pragma unroll
            for (int px = 0; px < 4; ++px) qri[px] = qx[px] * r[i];
#pragma unroll
            for (int j = 0; j < K; ++j) {
#pragma unroll
                for (int px = 0; px < 4; ++px) {
                    const float e = __expf(fmaf(qx[px], kr[px + j], qri[px]));
                    den[px] += e;
                    num[px] = fmaf(e, vr[px + j], num[px]);
                }
            }
        }
    } else {
        float qrj[4][K];
#pragma unroll
        for (int px = 0; px < 4; ++px)
#pragma unroll
            for (int j = 0; j < K; ++j) qrj[px][j] = qx[px] * r[j];
#pragma unroll
        for (int i = 0; i < K; ++i) {
            const float4 ka = *(const float4*)&sk[lr + i][w0];
            const float4 kc = *(const float4*)&sk[lr + i][w0 + 4];
            const float4 va = *(const float4*)&sv[lr + i][w0];
            const float4 vc = *(const float4*)&sv[lr + i][w0 + 4];
            const float kr[8] = {ka.x, ka.y, ka.z, ka.w, kc.x, kc.y, kc.z, kc.w};
            const float vr[8] = {va.x, va.y, va.z, va.w, vc.x, vc.y, vc.z, vc.w};
#pragma unroll
            for (int j = 0; j < K; ++j) {
#pragma unroll
                for (int px = 0; px < 4; ++px) {
                    const float e = __expf(fmaf(qx[px], kr[px + j], qrj[px][j]));
                    den[px] += e;
                    num[px] = fmaf(e, vr[px + j], num[px]);
                }
            }
        }
    }

    float4 o;
    o.x = num[0] * __builtin_amdgcn_rcpf(den[0]);
    o.y = num[1] * __builtin_amdgcn_rcpf(den[1]);
    o.z = num[2] * __builtin_amdgcn_rcpf(den[2]);
    o.w = num[3] * __builtin_amdgcn_rcpf(den[3]);
    *(float4*)(out + pl * HW + h * W + w0) = o;
}

// ---------------------------------------------------------------------------
extern "C" void kernel_launch(void* const* d_in, const int* in_sizes, int n_in,
                              void* d_out, int out_size, void* d_ws, size_t ws_size,
                              hipStream_t stream)
{
    const float* x     = (const float*)d_in[0];
    const float* Wq    = (const float*)d_in[1];
    const float* Wk    = (const float*)d_in[2];
    const float* Wv    = (const float*)d_in[3];
    const float* rel_h = (const float*)d_in[4];
    const float* rel_w = (const float*)d_in[5];

    float* qb = (float*)d_ws;        // [B,C,64,64]  8 MB
    float* kb = qb + TOT;            // [B,C,64,64]  8 MB
    float* vb = kb + TOT;            // [B,C,64,64]  8 MB

    dim3 g1(B * HW / 256, 12);
    qkv_kernel<<<g1, 256, 0, stream>>>(x, Wq, Wk, Wv, qb, kb, vb);

    attn_kernel<<<B * C * 4, 256, 0, stream>>>(qb, kb, vb, rel_h, rel_w,
                                               (float*)d_out);
}